// Round 1
// baseline (892.797 us; speedup 1.0000x reference)
//
#include <hip/hip_runtime.h>

#define LW   64
#define HS   68     // padded LDS row stride (floats): 16B-aligned, p4-spacing 272w -> 2-way banks (free)
#define NBS  20     // noise tile row stride (floats)

// ---------- activations (fp32, hw transcendentals) ----------
__device__ __forceinline__ float act_tanh(float x){
    float t = __expf(-2.0f * fabsf(x));
    float y = (1.0f - t) / (1.0f + t);
    return copysignf(y, x);
}
__device__ __forceinline__ float act_elu(float x){
    return x > 0.0f ? x : __expf(x) - 1.0f;
}
__device__ __forceinline__ float act_softplus(float x){
    float a = fabsf(x);
    return fmaxf(x, 0.0f) + __logf(1.0f + __expf(-a));
}
__device__ __forceinline__ float act_gauss(float x){
    return __expf(-0.5f * x * x);
}
__device__ __forceinline__ float act_sigmoid(float x){
    return 1.0f / (1.0f + __expf(-x));
}
template<int A> __device__ __forceinline__ float act(float v){
    if constexpr (A == 0) return act_tanh(v);
    else if constexpr (A == 1) return act_elu(v);
    else if constexpr (A == 2) return act_softplus(v);
    else if constexpr (A == 3) return __sinf(v);
    else if constexpr (A == 4) return act_gauss(v);
    else                       return act_sigmoid(v);
}

// ---------- one graph node: dst = ACT( (A0[+A1][+A2]) @ W + bias ) ----------
// 64p x 64j output per block; per thread 4p x 4j register tile.
template<int ACT, int NPRED>
__device__ __forceinline__ void node_op(const float* A0, const float* A1, const float* A2,
                                        const float* wb, const float* __restrict__ bias,
                                        float* dst, int p_base, int j_base)
{
    float acc[4][4];
    float4 bv = *(const float4*)(bias + j_base);
    #pragma unroll
    for (int pi = 0; pi < 4; ++pi){
        acc[pi][0] = bv.x; acc[pi][1] = bv.y; acc[pi][2] = bv.z; acc[pi][3] = bv.w;
    }
    #pragma unroll
    for (int kc = 0; kc < 16; ++kc){
        float a[4][4];
        #pragma unroll
        for (int pi = 0; pi < 4; ++pi){
            const int row = (p_base + pi) * HS + kc * 4;
            float4 v = *(const float4*)(A0 + row);
            if constexpr (NPRED >= 2){
                float4 u = *(const float4*)(A1 + row);
                v.x += u.x; v.y += u.y; v.z += u.z; v.w += u.w;
            }
            if constexpr (NPRED >= 3){
                float4 u = *(const float4*)(A2 + row);
                v.x += u.x; v.y += u.y; v.z += u.z; v.w += u.w;
            }
            a[pi][0] = v.x; a[pi][1] = v.y; a[pi][2] = v.z; a[pi][3] = v.w;
        }
        float w[4][4];
        #pragma unroll
        for (int kk = 0; kk < 4; ++kk){
            float4 v = *(const float4*)(wb + (kc * 4 + kk) * LW + j_base);
            w[kk][0] = v.x; w[kk][1] = v.y; w[kk][2] = v.z; w[kk][3] = v.w;
        }
        #pragma unroll
        for (int pi = 0; pi < 4; ++pi)
            #pragma unroll
            for (int kk = 0; kk < 4; ++kk)
                #pragma unroll
                for (int ji = 0; ji < 4; ++ji)
                    acc[pi][ji] = fmaf(a[pi][kk], w[kk][ji], acc[pi][ji]);
    }
    #pragma unroll
    for (int pi = 0; pi < 4; ++pi){
        float4 o;
        o.x = act<ACT>(acc[pi][0]);
        o.y = act<ACT>(acc[pi][1]);
        o.z = act<ACT>(acc[pi][2]);
        o.w = act<ACT>(acc[pi][3]);
        *(float4*)(dst + (p_base + pi) * HS + j_base) = o;
    }
}

__global__ __launch_bounds__(256, 1) void inr_graph_kernel(
    const float* __restrict__ gx, const float* __restrict__ gy,
    const float* __restrict__ gz, const float* __restrict__ gr,
    const float* __restrict__ gnoise,
    const float* __restrict__ W_noise, const float* __restrict__ b_noise,
    const float* __restrict__ W_x, const float* __restrict__ W_y,
    const float* __restrict__ W_z, const float* __restrict__ W_r,
    const float* __restrict__ W1, const float* __restrict__ b1,
    const float* __restrict__ Wg, const float* __restrict__ bg,
    const float* __restrict__ W_out, const float* __restrict__ b_out,
    float* __restrict__ out)
{
    // h0 pinned + 4-slot ring (graph reads lags {1,3} and h0 only)
    __shared__ __align__(16) float hb0[LW * HS];
    __shared__ __align__(16) float rg0[LW * HS];
    __shared__ __align__(16) float rg1[LW * HS];
    __shared__ __align__(16) float rg2[LW * HS];
    __shared__ __align__(16) float rg3[LW * HS];
    __shared__ __align__(16) float wbuf[LW * LW];     // current 64x64 weight
    __shared__ __align__(16) float nbuf[LW * NBS];    // noise tile 64x16 (padded)
    __shared__ float sc[4][LW];                       // x,y,z,r scalars for 64 points
    __shared__ __align__(16) float wv[4][LW];         // W_x,W_y,W_z,W_r
    __shared__ float wout_s[LW * 3];
    __shared__ float bout_s[4];

    const int tid    = threadIdx.x;
    const int j4     = tid & 15;
    const int p4     = tid >> 4;
    const int j_base = j4 * 4;
    const int p_base = p4 * 4;
    const int blk_p0 = blockIdx.x * LW;

    // ---- stage block inputs ----
    {
        const float4* n4 = (const float4*)(gnoise + (size_t)blk_p0 * 16);
        float4 v = n4[tid];                                  // 1024 floats, coalesced
        const int p = tid >> 2, k4 = tid & 3;
        *(float4*)(nbuf + p * NBS + k4 * 4) = v;
        ((float4*)wbuf)[tid] = ((const float4*)W_noise)[tid]; // 16x64 into wbuf
    }
    if (tid < LW){
        sc[0][tid] = gx[blk_p0 + tid];
        sc[1][tid] = gy[blk_p0 + tid];
        sc[2][tid] = gz[blk_p0 + tid];
        sc[3][tid] = gr[blk_p0 + tid];
        wv[0][tid] = W_x[tid];
        wv[1][tid] = W_y[tid];
        wv[2][tid] = W_z[tid];
        wv[3][tid] = W_r[tid];
    }
    if (tid < LW * 3) wout_s[tid] = W_out[tid];
    if (tid < 3)      bout_s[tid] = b_out[tid];
    __syncthreads();

    // ---- phase 1: g = sin(elu(z Wz) + gauss(x Wx) + tanh(y Wy) + softplus(r Wr) + tanh(noise Wn + bn)) ----
    {
        float acc[4][4];
        float4 bv = *(const float4*)(b_noise + j_base);
        #pragma unroll
        for (int pi = 0; pi < 4; ++pi){
            acc[pi][0] = bv.x; acc[pi][1] = bv.y; acc[pi][2] = bv.z; acc[pi][3] = bv.w;
        }
        #pragma unroll
        for (int kc = 0; kc < 4; ++kc){
            float a[4][4];
            #pragma unroll
            for (int pi = 0; pi < 4; ++pi){
                float4 v = *(const float4*)(nbuf + (p_base + pi) * NBS + kc * 4);
                a[pi][0] = v.x; a[pi][1] = v.y; a[pi][2] = v.z; a[pi][3] = v.w;
            }
            float w[4][4];
            #pragma unroll
            for (int kk = 0; kk < 4; ++kk){
                float4 v = *(const float4*)(wbuf + (kc * 4 + kk) * LW + j_base);
                w[kk][0] = v.x; w[kk][1] = v.y; w[kk][2] = v.z; w[kk][3] = v.w;
            }
            #pragma unroll
            for (int pi = 0; pi < 4; ++pi)
                #pragma unroll
                for (int kk = 0; kk < 4; ++kk)
                    #pragma unroll
                    for (int ji = 0; ji < 4; ++ji)
                        acc[pi][ji] = fmaf(a[pi][kk], w[kk][ji], acc[pi][ji]);
        }
        float wxa[4], wya[4], wza[4], wra[4];
        {
            float4 v;
            v = *(const float4*)&wv[0][j_base]; wxa[0]=v.x; wxa[1]=v.y; wxa[2]=v.z; wxa[3]=v.w;
            v = *(const float4*)&wv[1][j_base]; wya[0]=v.x; wya[1]=v.y; wya[2]=v.z; wya[3]=v.w;
            v = *(const float4*)&wv[2][j_base]; wza[0]=v.x; wza[1]=v.y; wza[2]=v.z; wza[3]=v.w;
            v = *(const float4*)&wv[3][j_base]; wra[0]=v.x; wra[1]=v.y; wra[2]=v.z; wra[3]=v.w;
        }
        #pragma unroll
        for (int pi = 0; pi < 4; ++pi){
            const int p = p_base + pi;
            const float xs = sc[0][p], ys = sc[1][p], zs = sc[2][p], rs = sc[3][p];
            float o[4];
            #pragma unroll
            for (int ji = 0; ji < 4; ++ji){
                float v = act_elu(zs * wza[ji])
                        + act_gauss(xs * wxa[ji])
                        + act_tanh(ys * wya[ji])
                        + act_softplus(rs * wra[ji])
                        + act_tanh(acc[pi][ji]);
                o[ji] = __sinf(v);
            }
            float4 ov; ov.x = o[0]; ov.y = o[1]; ov.z = o[2]; ov.w = o[3];
            *(float4*)(rg3 + p * HS + j_base) = ov;   // g staged in rg3 (dead after W1 matmul)
        }
    }

    // stage a 64x64 weight into wbuf (guarded both sides)
    #define STAGE_W(SRC) do { \
        __syncthreads(); \
        const float4* s4_ = (const float4*)(SRC); \
        float4* w4_ = (float4*)wbuf; \
        w4_[tid]       = s4_[tid]; \
        w4_[tid + 256] = s4_[tid + 256]; \
        w4_[tid + 512] = s4_[tid + 512]; \
        w4_[tid + 768] = s4_[tid + 768]; \
        __syncthreads(); \
    } while (0)

    // h0 = tanh(g @ W1 + b1)
    STAGE_W(W1);
    node_op<0,1>(rg3, nullptr, nullptr, wbuf, b1, hb0, p_base, j_base);

    // graph nodes: h_n slot = ring[(n-1)%4]; acts cycle tanh,elu,softplus,sin,gauss,sigmoid
    STAGE_W(Wg + 0*4096);  node_op<0,1>(hb0, nullptr, nullptr, wbuf, bg +   0, rg0, p_base, j_base); // h1
    STAGE_W(Wg + 1*4096);  node_op<1,1>(rg0, nullptr, nullptr, wbuf, bg +  64, rg1, p_base, j_base); // h2
    STAGE_W(Wg + 2*4096);  node_op<2,2>(rg1, hb0,    nullptr, wbuf, bg + 128, rg2, p_base, j_base); // h3 = (h2+h0)
    STAGE_W(Wg + 3*4096);  node_op<3,3>(rg2, rg0,    hb0,     wbuf, bg + 192, rg3, p_base, j_base); // h4 = (h3+h1+h0)
    STAGE_W(Wg + 4*4096);  node_op<4,2>(rg3, rg1,    nullptr, wbuf, bg + 256, rg0, p_base, j_base); // h5 = (h4+h2)
    STAGE_W(Wg + 5*4096);  node_op<5,2>(rg0, rg2,    nullptr, wbuf, bg + 320, rg1, p_base, j_base); // h6 = (h5+h3)
    STAGE_W(Wg + 6*4096);  node_op<0,2>(rg1, rg3,    nullptr, wbuf, bg + 384, rg2, p_base, j_base); // h7 = (h6+h4)
    STAGE_W(Wg + 7*4096);  node_op<1,3>(rg2, rg0,    hb0,     wbuf, bg + 448, rg3, p_base, j_base); // h8 = (h7+h5+h0)
    STAGE_W(Wg + 8*4096);  node_op<2,2>(rg3, rg1,    nullptr, wbuf, bg + 512, rg0, p_base, j_base); // h9 = (h8+h6)
    STAGE_W(Wg + 9*4096);  node_op<3,2>(rg0, rg2,    nullptr, wbuf, bg + 576, rg1, p_base, j_base); // h10= (h9+h7)
    STAGE_W(Wg + 10*4096); node_op<4,2>(rg1, rg3,    nullptr, wbuf, bg + 640, rg2, p_base, j_base); // h11= (h10+h8)
    __syncthreads();

    // ---- output: sigmoid(h11 @ W_out + b_out), h11 in rg2 ----
    if (tid < LW * 3){
        const int p = tid / 3, c = tid - p * 3;
        float acc2 = bout_s[c];
        const float* hrow = rg2 + p * HS;
        #pragma unroll
        for (int k = 0; k < LW; ++k)
            acc2 = fmaf(hrow[k], wout_s[k * 3 + c], acc2);
        out[(size_t)(blk_p0 + p) * 3 + c] = act_sigmoid(acc2);
    }
    #undef STAGE_W
}

extern "C" void kernel_launch(void* const* d_in, const int* in_sizes, int n_in,
                              void* d_out, int out_size, void* d_ws, size_t ws_size,
                              hipStream_t stream)
{
    const float* x       = (const float*)d_in[0];
    const float* y       = (const float*)d_in[1];
    const float* z       = (const float*)d_in[2];
    const float* r       = (const float*)d_in[3];
    const float* noise   = (const float*)d_in[4];
    const float* W_noise = (const float*)d_in[5];
    const float* b_noise = (const float*)d_in[6];
    const float* W_x     = (const float*)d_in[7];
    const float* W_y     = (const float*)d_in[8];
    const float* W_z     = (const float*)d_in[9];
    const float* W_r     = (const float*)d_in[10];
    const float* W1      = (const float*)d_in[11];
    const float* b1      = (const float*)d_in[12];
    const float* Wg      = (const float*)d_in[13];
    const float* bg      = (const float*)d_in[14];
    const float* W_out   = (const float*)d_in[15];
    const float* b_out   = (const float*)d_in[16];
    float* out = (float*)d_out;

    const int n = in_sizes[0];
    const int blocks = n / LW;
    inr_graph_kernel<<<dim3(blocks), dim3(256), 0, stream>>>(
        x, y, z, r, noise, W_noise, b_noise, W_x, W_y, W_z, W_r,
        W1, b1, Wg, bg, W_out, b_out, out);
}

// Round 2
// 282.260 us; speedup vs baseline: 3.1630x; 3.1630x over previous
//
#include <hip/hip_runtime.h>

#define LW 64
#define SCR 72     // scratch feature stride (fp16): 144 B rows -> 16B-aligned b128 reads

typedef _Float16 f16;
typedef f16  f16x8 __attribute__((ext_vector_type(8)));
typedef f16  f16x2 __attribute__((ext_vector_type(2)));
typedef float f32x4 __attribute__((ext_vector_type(4)));

// ---------- activations (fp32, identical to validated R1) ----------
__device__ __forceinline__ float act_tanh(float x){
    float t = __expf(-2.0f * fabsf(x));
    float y = (1.0f - t) / (1.0f + t);
    return copysignf(y, x);
}
__device__ __forceinline__ float act_elu(float x){
    return x > 0.0f ? x : __expf(x) - 1.0f;
}
__device__ __forceinline__ float act_softplus(float x){
    float a = fabsf(x);
    return fmaxf(x, 0.0f) + __logf(1.0f + __expf(-a));
}
__device__ __forceinline__ float act_gauss(float x){
    return __expf(-0.5f * x * x);
}
__device__ __forceinline__ float act_sigmoid(float x){
    return 1.0f / (1.0f + __expf(-x));
}
template<int A> __device__ __forceinline__ float act(float v){
    if constexpr (A == 0) return act_tanh(v);
    else if constexpr (A == 1) return act_elu(v);
    else if constexpr (A == 2) return act_softplus(v);
    else if constexpr (A == 3) return __sinf(v);
    else if constexpr (A == 4) return act_gauss(v);
    else                       return act_sigmoid(v);
}

#define MFMA(a, b, c) __builtin_amdgcn_mfma_f32_16x16x32_f16((a), (b), (c), 0, 0, 0)
#define INV2048 4.8828125e-4f

__global__ __launch_bounds__(512, 2) void inr_mfma_kernel(
    const float* __restrict__ gx, const float* __restrict__ gy,
    const float* __restrict__ gz, const float* __restrict__ gr,
    const float* __restrict__ gnoise,
    const float* __restrict__ W_noise, const float* __restrict__ b_noise,
    const float* __restrict__ W_x, const float* __restrict__ W_y,
    const float* __restrict__ W_z, const float* __restrict__ W_r,
    const float* __restrict__ W1, const float* __restrict__ b1,
    const float* __restrict__ Wg, const float* __restrict__ bg,
    const float* __restrict__ W_out, const float* __restrict__ b_out,
    float* __restrict__ out)
{
    // ---- LDS: 145.4 KB total ----
    __shared__ __align__(16) f16   wfrag[12][4][2][64][8]; // 96 KB  W^T A-frags  [node][itile][kstep][lane][j]
    __shared__ __align__(16) f16   nfrag[4][64][8];        //  4 KB  W_noise^T (+bias row k=16, zeros k>16)
    __shared__ __align__(16) f16   ofrag[2][64][8];        //  2 KB  W_out^T (rows >=3 zero)
    __shared__ __align__(16) float bfrag[12][4][4][4];     //  3 KB  biases in frag order [node][t][q][r]
    __shared__ __align__(16) float wvfrag[4][4][4][4];     //  1 KB  Wx,Wy,Wz,Wr in frag order
    __shared__            float bout_s[4];
    __shared__ __align__(16) f16   scratch[8][2][16][SCR]; // 36.9 KB per-wave transpose scratch [wave][hi/lo][pt][feat]

    const int tid  = threadIdx.x;
    const int lane = tid & 63;
    const int wv   = tid >> 6;       // wave id 0..7
    const int n    = lane & 15;      // point-in-tile (MFMA col)
    const int q    = lane >> 4;      // quad

    // ================= PREP: build fragments in LDS =================
    for (int i = tid; i < 12 * 64; i += 512){
        int node = i >> 6, f = i & 63;
        bfrag[node][(f >> 4) & 3][(f >> 2) & 3][f & 3] = (node == 0) ? b1[f] : bg[(node - 1) * 64 + f];
    }
    for (int i = tid; i < 4 * 64; i += 512){
        int vec = i >> 6, f = i & 63;
        const float* src = (vec == 0) ? W_x : (vec == 1) ? W_y : (vec == 2) ? W_z : W_r;
        wvfrag[vec][(f >> 4) & 3][(f >> 2) & 3][f & 3] = src[f];
    }
    if (tid < 4) bout_s[tid] = (tid < 3) ? b_out[tid] : 0.0f;
    for (int i = tid; i < 2048; i += 512){           // nfrag
        int j = i & 7, ln = (i >> 3) & 63, t = i >> 9;
        int k = ((ln >> 4) & 3) * 8 + j, m = t * 16 + (ln & 15);
        float v = (k < 16) ? W_noise[k * 64 + m] : ((k == 16) ? b_noise[m] : 0.0f);
        nfrag[t][ln][j] = (f16)v;
    }
    for (int i = tid; i < 1024; i += 512){           // ofrag
        int j = i & 7, ln = (i >> 3) & 63, s = i >> 9;
        int k = s * 32 + ((ln >> 4) & 3) * 8 + j, c = ln & 15;
        float v = (c < 3) ? W_out[k * 3 + c] : 0.0f;
        ofrag[s][ln][j] = (f16)v;
    }
    // big weights: coalesced stage into scratch (as raw fp32), then frag-fill
    {
        float* wraw = (float*)&scratch[0][0][0][0];  // 16 KB <= 36.9 KB
        for (int node = 0; node < 12; ++node){
            const float* Wsrc = (node == 0) ? W1 : (Wg + (node - 1) * 4096);
            __syncthreads();                          // protect wraw (prev iter readers)
            ((float4*)wraw)[tid]       = ((const float4*)Wsrc)[tid];
            ((float4*)wraw)[tid + 512] = ((const float4*)Wsrc)[tid + 512];
            __syncthreads();
            const int L  = tid * 8;                   // 4096 f16 per node, 8 per thread
            const int ln = (L >> 3) & 63;
            const int s  = (L >> 9) & 1;
            const int t  = L >> 10;
            const int kb = ((ln >> 4) & 3) * 8 + s * 32;
            const int m  = t * 16 + (ln & 15);
            f16x8 vvv;
            #pragma unroll
            for (int j = 0; j < 8; ++j) vvv[j] = (f16)wraw[(kb + j) * 64 + m];
            *(f16x8*)&wfrag[node][t][s][ln][0] = vvv;
        }
        __syncthreads();   // wfrag complete; scratch now free for per-wave use
    }

    // helper macros -------------------------------------------------
    // transpose 16 fp32 values v[t][r] (features 16t+4q+r of point n) into hi/lo B-frags
    #define XPOSE(VARR, DSTH, DSTL) do {                                           \
        _Pragma("unroll")                                                          \
        for (int t_ = 0; t_ < 4; ++t_){                                            \
            f16 h0_ = (f16)VARR[t_][0], h1_ = (f16)VARR[t_][1];                    \
            f16 h2_ = (f16)VARR[t_][2], h3_ = (f16)VARR[t_][3];                    \
            f16 l0_ = (f16)((VARR[t_][0] - (float)h0_) * 2048.0f);                 \
            f16 l1_ = (f16)((VARR[t_][1] - (float)h1_) * 2048.0f);                 \
            f16 l2_ = (f16)((VARR[t_][2] - (float)h2_) * 2048.0f);                 \
            f16 l3_ = (f16)((VARR[t_][3] - (float)h3_) * 2048.0f);                 \
            *(f16x2*)&scratch[wv][0][n][t_ * 16 + q * 4]     = (f16x2){h0_, h1_};  \
            *(f16x2*)&scratch[wv][0][n][t_ * 16 + q * 4 + 2] = (f16x2){h2_, h3_};  \
            *(f16x2*)&scratch[wv][1][n][t_ * 16 + q * 4]     = (f16x2){l0_, l1_};  \
            *(f16x2*)&scratch[wv][1][n][t_ * 16 + q * 4 + 2] = (f16x2){l2_, l3_};  \
        }                                                                          \
        _Pragma("unroll")                                                          \
        for (int s_ = 0; s_ < 2; ++s_){                                            \
            DSTH[s_] = *(const f16x8*)&scratch[wv][0][n][s_ * 32 + q * 8];         \
            DSTL[s_] = *(const f16x8*)&scratch[wv][1][n][s_ * 32 + q * 8];         \
        }                                                                          \
    } while (0)

    #define NODE_ACC_INIT(NODEI)                                                   \
        f32x4 am_[4], al_[4];                                                      \
        _Pragma("unroll")                                                          \
        for (int t_ = 0; t_ < 4; ++t_){                                            \
            am_[t_] = *(const f32x4*)&bfrag[NODEI][t_][q][0];                      \
            al_[t_] = (f32x4){0.f, 0.f, 0.f, 0.f};                                 \
        }

    #define NODE_MM1(NODEI, P0H, P0L)                                              \
        _Pragma("unroll")                                                          \
        for (int s_ = 0; s_ < 2; ++s_){                                            \
            f16x8 Af_[4];                                                          \
            _Pragma("unroll")                                                      \
            for (int t_ = 0; t_ < 4; ++t_) Af_[t_] = *(const f16x8*)&wfrag[NODEI][t_][s_][lane][0]; \
            _Pragma("unroll")                                                      \
            for (int t_ = 0; t_ < 4; ++t_){                                        \
                am_[t_] = MFMA(Af_[t_], P0H[s_], am_[t_]);                         \
                al_[t_] = MFMA(Af_[t_], P0L[s_], al_[t_]);                         \
            }                                                                      \
        }

    #define NODE_MM2(NODEI, P0H, P0L, P1H, P1L)                                    \
        _Pragma("unroll")                                                          \
        for (int s_ = 0; s_ < 2; ++s_){                                            \
            f16x8 Af_[4];                                                          \
            _Pragma("unroll")                                                      \
            for (int t_ = 0; t_ < 4; ++t_) Af_[t_] = *(const f16x8*)&wfrag[NODEI][t_][s_][lane][0]; \
            _Pragma("unroll")                                                      \
            for (int t_ = 0; t_ < 4; ++t_){                                        \
                am_[t_] = MFMA(Af_[t_], P0H[s_], am_[t_]);                         \
                al_[t_] = MFMA(Af_[t_], P0L[s_], al_[t_]);                         \
                am_[t_] = MFMA(Af_[t_], P1H[s_], am_[t_]);                         \
                al_[t_] = MFMA(Af_[t_], P1L[s_], al_[t_]);                         \
            }                                                                      \
        }

    #define NODE_MM3(NODEI, P0H, P0L, P1H, P1L, P2H, P2L)                          \
        _Pragma("unroll")                                                          \
        for (int s_ = 0; s_ < 2; ++s_){                                            \
            f16x8 Af_[4];                                                          \
            _Pragma("unroll")                                                      \
            for (int t_ = 0; t_ < 4; ++t_) Af_[t_] = *(const f16x8*)&wfrag[NODEI][t_][s_][lane][0]; \
            _Pragma("unroll")                                                      \
            for (int t_ = 0; t_ < 4; ++t_){                                        \
                am_[t_] = MFMA(Af_[t_], P0H[s_], am_[t_]);                         \
                al_[t_] = MFMA(Af_[t_], P0L[s_], al_[t_]);                         \
                am_[t_] = MFMA(Af_[t_], P1H[s_], am_[t_]);                         \
                al_[t_] = MFMA(Af_[t_], P1L[s_], al_[t_]);                         \
                am_[t_] = MFMA(Af_[t_], P2H[s_], am_[t_]);                         \
                al_[t_] = MFMA(Af_[t_], P2L[s_], al_[t_]);                         \
            }                                                                      \
        }

    #define NODE_FINISH(ACTI, DSTH, DSTL) do {                                     \
        float vv_[4][4];                                                           \
        _Pragma("unroll")                                                          \
        for (int t_ = 0; t_ < 4; ++t_)                                             \
            _Pragma("unroll")                                                      \
            for (int r_ = 0; r_ < 4; ++r_)                                         \
                vv_[t_][r_] = act<ACTI>(am_[t_][r_] + al_[t_][r_] * INV2048);      \
        XPOSE(vv_, DSTH, DSTL);                                                    \
    } while (0)

    // slot registers: h0 + ring of 4, each hi[2]+lo[2] B-frags
    f16x8 sh0h[2], sh0l[2];
    f16x8 r0h[2], r0l[2], r1h[2], r1l[2], r2h[2], r2l[2], r3h[2], r3l[2];

    // ================= MAIN LOOP: 4 tiles of 16 points per wave =================
    for (int iter = 0; iter < 4; ++iter){
        const int tile = blockIdx.x * 32 + iter * 8 + wv;
        const int myp  = tile * 16 + n;

        // ---- input branches ----
        const float xs = gx[myp], ys = gy[myp], zs = gz[myp], rs = gr[myp];
        f16x8 nbh, nbl;
        if (q < 2){
            const float4 a4 = *(const float4*)(gnoise + myp * 16 + q * 8);
            const float4 b4 = *(const float4*)(gnoise + myp * 16 + q * 8 + 4);
            float nvv[8] = {a4.x, a4.y, a4.z, a4.w, b4.x, b4.y, b4.z, b4.w};
            #pragma unroll
            for (int j = 0; j < 8; ++j){
                nbh[j] = (f16)nvv[j];
                nbl[j] = (f16)((nvv[j] - (float)nbh[j]) * 2048.0f);
            }
        } else {
            #pragma unroll
            for (int j = 0; j < 8; ++j){ nbh[j] = (f16)0.0f; nbl[j] = (f16)0.0f; }
            if (q == 2) nbh[0] = (f16)1.0f;   // bias row k=16
        }
        float gval[4][4];
        {
            f32x4 am_[4], al_[4];
            #pragma unroll
            for (int t_ = 0; t_ < 4; ++t_){
                am_[t_] = (f32x4){0.f, 0.f, 0.f, 0.f};
                al_[t_] = (f32x4){0.f, 0.f, 0.f, 0.f};
                f16x8 Af_ = *(const f16x8*)&nfrag[t_][lane][0];
                am_[t_] = MFMA(Af_, nbh, am_[t_]);
                al_[t_] = MFMA(Af_, nbl, al_[t_]);
            }
            #pragma unroll
            for (int t_ = 0; t_ < 4; ++t_){
                const float4 wx = *(const float4*)&wvfrag[0][t_][q][0];
                const float4 wy = *(const float4*)&wvfrag[1][t_][q][0];
                const float4 wz = *(const float4*)&wvfrag[2][t_][q][0];
                const float4 wr = *(const float4*)&wvfrag[3][t_][q][0];
                const float wxa[4] = {wx.x, wx.y, wx.z, wx.w};
                const float wya[4] = {wy.x, wy.y, wy.z, wy.w};
                const float wza[4] = {wz.x, wz.y, wz.z, wz.w};
                const float wra[4] = {wr.x, wr.y, wr.z, wr.w};
                #pragma unroll
                for (int r_ = 0; r_ < 4; ++r_){
                    float pre = am_[t_][r_] + al_[t_][r_] * INV2048;   // noise@Wn + bn
                    float v = act_elu(zs * wza[r_])
                            + act_gauss(xs * wxa[r_])
                            + act_tanh(ys * wya[r_])
                            + act_softplus(rs * wra[r_])
                            + act_tanh(pre);
                    gval[t_][r_] = __sinf(v);
                }
            }
        }
        f16x8 sgh[2], sgl[2];
        XPOSE(gval, sgh, sgl);

        // h0 = tanh(g @ W1 + b1)
        { NODE_ACC_INIT(0);  NODE_MM1(0, sgh, sgl);                      NODE_FINISH(0, sh0h, sh0l); }
        // graph nodes (acts cycle tanh,elu,softplus,sin,gauss,sigmoid)
        { NODE_ACC_INIT(1);  NODE_MM1(1, sh0h, sh0l);                    NODE_FINISH(0, r0h, r0l); } // h1
        { NODE_ACC_INIT(2);  NODE_MM1(2, r0h, r0l);                      NODE_FINISH(1, r1h, r1l); } // h2
        { NODE_ACC_INIT(3);  NODE_MM2(3, r1h, r1l, sh0h, sh0l);          NODE_FINISH(2, r2h, r2l); } // h3 = h2+h0
        { NODE_ACC_INIT(4);  NODE_MM3(4, r2h, r2l, r0h, r0l, sh0h, sh0l);NODE_FINISH(3, r3h, r3l); } // h4 = h3+h1+h0
        { NODE_ACC_INIT(5);  NODE_MM2(5, r3h, r3l, r1h, r1l);            NODE_FINISH(4, r0h, r0l); } // h5 = h4+h2
        { NODE_ACC_INIT(6);  NODE_MM2(6, r0h, r0l, r2h, r2l);            NODE_FINISH(5, r1h, r1l); } // h6 = h5+h3
        { NODE_ACC_INIT(7);  NODE_MM2(7, r1h, r1l, r3h, r3l);            NODE_FINISH(0, r2h, r2l); } // h7 = h6+h4
        { NODE_ACC_INIT(8);  NODE_MM3(8, r2h, r2l, r0h, r0l, sh0h, sh0l);NODE_FINISH(1, r3h, r3l); } // h8 = h7+h5+h0
        { NODE_ACC_INIT(9);  NODE_MM2(9, r3h, r3l, r1h, r1l);            NODE_FINISH(2, r0h, r0l); } // h9 = h8+h6
        { NODE_ACC_INIT(10); NODE_MM2(10, r0h, r0l, r2h, r2l);           NODE_FINISH(3, r1h, r1l); } // h10= h9+h7
        { NODE_ACC_INIT(11); NODE_MM2(11, r1h, r1l, r3h, r3l);           NODE_FINISH(4, r2h, r2l); } // h11= h10+h8

        // ---- output: sigmoid(h11 @ W_out + b_out), h11 in r2 ----
        {
            f32x4 om = (f32x4){0.f, 0.f, 0.f, 0.f};
            f32x4 ol = (f32x4){0.f, 0.f, 0.f, 0.f};
            #pragma unroll
            for (int s_ = 0; s_ < 2; ++s_){
                f16x8 Af_ = *(const f16x8*)&ofrag[s_][lane][0];
                om = MFMA(Af_, r2h[s_], om);
                ol = MFMA(Af_, r2l[s_], ol);
            }
            if (q == 0){
                #pragma unroll
                for (int r_ = 0; r_ < 3; ++r_){
                    float val = om[r_] + ol[r_] * INV2048 + bout_s[r_];
                    out[myp * 3 + r_] = act_sigmoid(val);
                }
            }
        }
    }
}

extern "C" void kernel_launch(void* const* d_in, const int* in_sizes, int n_in,
                              void* d_out, int out_size, void* d_ws, size_t ws_size,
                              hipStream_t stream)
{
    const float* x       = (const float*)d_in[0];
    const float* y       = (const float*)d_in[1];
    const float* z       = (const float*)d_in[2];
    const float* r       = (const float*)d_in[3];
    const float* noise   = (const float*)d_in[4];
    const float* W_noise = (const float*)d_in[5];
    const float* b_noise = (const float*)d_in[6];
    const float* W_x     = (const float*)d_in[7];
    const float* W_y     = (const float*)d_in[8];
    const float* W_z     = (const float*)d_in[9];
    const float* W_r     = (const float*)d_in[10];
    const float* W1      = (const float*)d_in[11];
    const float* b1      = (const float*)d_in[12];
    const float* Wg      = (const float*)d_in[13];
    const float* bg      = (const float*)d_in[14];
    const float* W_out   = (const float*)d_in[15];
    const float* b_out   = (const float*)d_in[16];
    float* out = (float*)d_out;

    const int n = in_sizes[0];
    const int blocks = n / 512;         // 512 points per block (8 waves x 16 pts x 4 iters)
    inr_mfma_kernel<<<dim3(blocks), dim3(512), 0, stream>>>(
        x, y, z, r, noise, W_noise, b_noise, W_x, W_y, W_z, W_r,
        W1, b1, Wg, bg, W_out, b_out, out);
}

// Round 4
// 206.242 us; speedup vs baseline: 4.3289x; 1.3686x over previous
//
#include <hip/hip_runtime.h>

#define SCR 72     // scratch feature stride (f16): 144 B rows, 16B-aligned

typedef _Float16 f16;
typedef f16  f16x2 __attribute__((ext_vector_type(2)));
typedef f16  f16x4 __attribute__((ext_vector_type(4)));
typedef f16  f16x8 __attribute__((ext_vector_type(8)));
typedef __fp16 h16x2 __attribute__((ext_vector_type(2)));  // cvt_pkrtz native return type
typedef float f32x4 __attribute__((ext_vector_type(4)));

__device__ __forceinline__ float frcp(float x){
#if __has_builtin(__builtin_amdgcn_rcpf)
    return __builtin_amdgcn_rcpf(x);
#else
    return 1.0f / x;
#endif
}

// ---------- activations (fp32, rcp-based — no v_div sequences) ----------
__device__ __forceinline__ float act_tanh(float x){
    // 1 - 2/(e^{2x}+1): monotone, saturates correctly at +/-inf
    return 1.0f - 2.0f * frcp(1.0f + __expf(2.0f * x));
}
__device__ __forceinline__ float act_elu(float x){
    float e = __expf(x) - 1.0f;
    return x > 0.0f ? x : e;
}
__device__ __forceinline__ float act_softplus(float x){
    float a = fabsf(x);
    return fmaxf(x, 0.0f) + __logf(1.0f + __expf(-a));
}
__device__ __forceinline__ float act_gauss(float x){
    return __expf(-0.5f * x * x);
}
__device__ __forceinline__ float act_sigmoid(float x){
    return frcp(1.0f + __expf(-x));
}
template<int A> __device__ __forceinline__ float act(float v){
    if constexpr (A == 0) return act_tanh(v);
    else if constexpr (A == 1) return act_elu(v);
    else if constexpr (A == 2) return act_softplus(v);
    else if constexpr (A == 3) return __sinf(v);
    else if constexpr (A == 4) return act_gauss(v);
    else                       return act_sigmoid(v);
}

__device__ __forceinline__ f16x2 cvt2(float a, float b){
    h16x2 p = __builtin_amdgcn_cvt_pkrtz(a, b);
    return __builtin_bit_cast(f16x2, p);
}
__device__ __forceinline__ f16x4 pack4(float a, float b, float c, float d){
    f16x2 p0 = cvt2(a, b);
    f16x2 p1 = cvt2(c, d);
    f16x4 r; r[0] = p0[0]; r[1] = p0[1]; r[2] = p1[0]; r[3] = p1[1];
    return r;
}

#define MFMA(a, b, c) __builtin_amdgcn_mfma_f32_16x16x32_f16((a), (b), (c), 0, 0, 0)

__global__ __launch_bounds__(512, 2) void inr_mfma2_kernel(
    const float* __restrict__ gx, const float* __restrict__ gy,
    const float* __restrict__ gz, const float* __restrict__ gr,
    const float* __restrict__ gnoise,
    const float* __restrict__ W_noise, const float* __restrict__ b_noise,
    const float* __restrict__ W_x, const float* __restrict__ W_y,
    const float* __restrict__ W_z, const float* __restrict__ W_r,
    const float* __restrict__ W1, const float* __restrict__ b1,
    const float* __restrict__ Wg, const float* __restrict__ bg,
    const float* __restrict__ W_out, const float* __restrict__ b_out,
    float* __restrict__ out)
{
    // ---- LDS: ~124 KB total ----
    __shared__ __align__(16) f16   wfrag[12][4][2][64][8]; // 96 KB  W^T A-frags [node][t][s][lane][j]
    __shared__ __align__(16) f16   nfrag[4][64][8];        //  4 KB  W_noise^T (+bias row k=16)
    __shared__ __align__(16) f16   ofrag[2][64][8];        //  2 KB  W_out^T (rows >=3 zero)
    __shared__ __align__(16) float bfrag[12][4][4][4];     //  3 KB  biases in frag order
    __shared__ __align__(16) float wvfrag[4][4][4][4];     //  1 KB  Wx,Wy,Wz,Wr in frag order
    __shared__            float bout_s[4];
    __shared__ __align__(16) f16   scratch[8][16][SCR];    // 18.4 KB per-wave transpose scratch

    const int tid  = threadIdx.x;
    const int lane = tid & 63;
    const int wvid = tid >> 6;       // wave id 0..7
    const int n    = lane & 15;      // point-in-tile (MFMA col)
    const int q    = lane >> 4;      // quad

    // ================= PREP: build fragments in LDS =================
    for (int i = tid; i < 12 * 64; i += 512){
        int node = i >> 6, f = i & 63;
        bfrag[node][(f >> 4) & 3][(f >> 2) & 3][f & 3] = (node == 0) ? b1[f] : bg[(node - 1) * 64 + f];
    }
    for (int i = tid; i < 4 * 64; i += 512){
        int vec = i >> 6, f = i & 63;
        const float* src = (vec == 0) ? W_x : (vec == 1) ? W_y : (vec == 2) ? W_z : W_r;
        wvfrag[vec][(f >> 4) & 3][(f >> 2) & 3][f & 3] = src[f];
    }
    if (tid < 4) bout_s[tid] = (tid < 3) ? b_out[tid] : 0.0f;
    for (int i = tid; i < 2048; i += 512){           // nfrag
        int j = i & 7, ln = (i >> 3) & 63, t = i >> 9;
        int k = ((ln >> 4) & 3) * 8 + j, m = t * 16 + (ln & 15);
        float v = (k < 16) ? W_noise[k * 64 + m] : ((k == 16) ? b_noise[m] : 0.0f);
        nfrag[t][ln][j] = (f16)v;
    }
    for (int i = tid; i < 1024; i += 512){           // ofrag
        int j = i & 7, ln = (i >> 3) & 63, s = i >> 9;
        int k = s * 32 + ((ln >> 4) & 3) * 8 + j, c = ln & 15;
        float v = (c < 3) ? W_out[k * 3 + c] : 0.0f;
        ofrag[s][ln][j] = (f16)v;
    }
    // big weights: coalesced stage into scratch (raw fp32), then frag-fill
    {
        float* wraw = (float*)&scratch[0][0][0];     // 16 KB <= 18.4 KB
        for (int node = 0; node < 12; ++node){
            const float* Wsrc = (node == 0) ? W1 : (Wg + (node - 1) * 4096);
            __syncthreads();                          // protect wraw (prev iter readers)
            ((float4*)wraw)[tid]       = ((const float4*)Wsrc)[tid];
            ((float4*)wraw)[tid + 512] = ((const float4*)Wsrc)[tid + 512];
            __syncthreads();
            const int L  = tid * 8;                   // 4096 f16 per node, 8 per thread
            const int ln = (L >> 3) & 63;
            const int s  = (L >> 9) & 1;
            const int t  = L >> 10;
            const int kb = ((ln >> 4) & 3) * 8 + s * 32;
            const int m  = t * 16 + (ln & 15);
            f16x8 vvv;
            #pragma unroll
            for (int j = 0; j < 8; ++j) vvv[j] = (f16)wraw[(kb + j) * 64 + m];
            *(f16x8*)&wfrag[node][t][s][ln][0] = vvv;
        }
        __syncthreads();   // wfrag complete; scratch now free for per-wave use
    }

    // lane-constant scratch pointers (all steady-state offsets are immediates)
    f16*       swb = &scratch[wvid][n][4 * q];   // write: feat 16t+4q  -> swb + 16t
    const f16* srb = &scratch[wvid][n][8 * q];   // read:  feat 32s+8q  -> srb + 32s

    // one node: acc = bias; acc += W^T @ Bin (8 MFMAs); act; transpose via scratch -> OUT frags
    #define NODE_CORE(NI, ACTI, B0, B1, OUT) do {                                          \
        f32x4 ac_[4];                                                                      \
        _Pragma("unroll")                                                                  \
        for (int t_ = 0; t_ < 4; ++t_) ac_[t_] = *(const f32x4*)&bfrag[NI][t_][q][0];      \
        _Pragma("unroll")                                                                  \
        for (int t_ = 0; t_ < 4; ++t_)                                                     \
            ac_[t_] = MFMA(*(const f16x8*)&wfrag[NI][t_][0][lane][0], B0, ac_[t_]);        \
        _Pragma("unroll")                                                                  \
        for (int t_ = 0; t_ < 4; ++t_)                                                     \
            ac_[t_] = MFMA(*(const f16x8*)&wfrag[NI][t_][1][lane][0], B1, ac_[t_]);        \
        _Pragma("unroll")                                                                  \
        for (int t_ = 0; t_ < 4; ++t_)                                                     \
            *(f16x4*)(swb + 16 * t_) = pack4(act<ACTI>(ac_[t_][0]), act<ACTI>(ac_[t_][1]), \
                                             act<ACTI>(ac_[t_][2]), act<ACTI>(ac_[t_][3]));\
        OUT[0] = *(const f16x8*)(srb);                                                     \
        OUT[1] = *(const f16x8*)(srb + 32);                                                \
    } while (0)

    #define NODE1(NI, ACTI, A, OUT)       do { NODE_CORE(NI, ACTI, A[0], A[1], OUT); } while (0)
    #define NODE2(NI, ACTI, A, B, OUT)    do { f16x8 s0_ = A[0] + B[0], s1_ = A[1] + B[1];          \
                                               NODE_CORE(NI, ACTI, s0_, s1_, OUT); } while (0)
    #define NODE3(NI, ACTI, A, B, C, OUT) do { f16x8 s0_ = A[0] + B[0] + C[0],                      \
                                                     s1_ = A[1] + B[1] + C[1];                      \
                                               NODE_CORE(NI, ACTI, s0_, s1_, OUT); } while (0)

    // ================= MAIN LOOP: 4 tiles of 16 points per wave =================
    for (int iter = 0; iter < 4; ++iter){
        const int tile = blockIdx.x * 32 + iter * 8 + wvid;
        const int myp  = tile * 16 + n;

        // ---- input branches ----
        const float xs = gx[myp], ys = gy[myp], zs = gz[myp], rs = gr[myp];
        f16x8 nb;
        if (q < 2){
            const float4 a4 = *(const float4*)(gnoise + (size_t)myp * 16 + q * 8);
            const float4 b4 = *(const float4*)(gnoise + (size_t)myp * 16 + q * 8 + 4);
            f16x2 p0 = cvt2(a4.x, a4.y);
            f16x2 p1 = cvt2(a4.z, a4.w);
            f16x2 p2 = cvt2(b4.x, b4.y);
            f16x2 p3 = cvt2(b4.z, b4.w);
            nb[0] = p0[0]; nb[1] = p0[1]; nb[2] = p1[0]; nb[3] = p1[1];
            nb[4] = p2[0]; nb[5] = p2[1]; nb[6] = p3[0]; nb[7] = p3[1];
        } else {
            #pragma unroll
            for (int j = 0; j < 8; ++j) nb[j] = (f16)0.0f;
            if (q == 2) nb[0] = (f16)1.0f;   // bias row k=16
        }
        // g = sin(elu(z Wz) + gauss(x Wx) + tanh(y Wy) + softplus(r Wr) + tanh(noise Wn + bn))
        float gv[4][4];
        {
            f32x4 am[4];
            #pragma unroll
            for (int t_ = 0; t_ < 4; ++t_){
                f32x4 zz = (f32x4){0.f, 0.f, 0.f, 0.f};
                am[t_] = MFMA(*(const f16x8*)&nfrag[t_][lane][0], nb, zz);
            }
            #pragma unroll
            for (int t_ = 0; t_ < 4; ++t_){
                const float4 wx = *(const float4*)&wvfrag[0][t_][q][0];
                const float4 wy = *(const float4*)&wvfrag[1][t_][q][0];
                const float4 wz = *(const float4*)&wvfrag[2][t_][q][0];
                const float4 wr = *(const float4*)&wvfrag[3][t_][q][0];
                const float wxa[4] = {wx.x, wx.y, wx.z, wx.w};
                const float wya[4] = {wy.x, wy.y, wy.z, wy.w};
                const float wza[4] = {wz.x, wz.y, wz.z, wz.w};
                const float wra[4] = {wr.x, wr.y, wr.z, wr.w};
                #pragma unroll
                for (int r_ = 0; r_ < 4; ++r_){
                    float v = act_elu(zs * wza[r_])
                            + act_gauss(xs * wxa[r_])
                            + act_tanh(ys * wya[r_])
                            + act_softplus(rs * wra[r_])
                            + act_tanh(am[t_][r_]);
                    gv[t_][r_] = __sinf(v);
                }
            }
        }
        f16x8 sg[2];
        #pragma unroll
        for (int t_ = 0; t_ < 4; ++t_)
            *(f16x4*)(swb + 16 * t_) = pack4(gv[t_][0], gv[t_][1], gv[t_][2], gv[t_][3]);
        sg[0] = *(const f16x8*)(srb);
        sg[1] = *(const f16x8*)(srb + 32);

        f16x8 h0[2], r0[2], r1[2], r2[2], r3[2];
        NODE1(0,  0, sg, h0);                 // h0 = tanh(g @ W1 + b1)
        NODE1(1,  0, h0, r0);                 // h1 = tanh(h0 W)
        NODE1(2,  1, r0, r1);                 // h2 = elu(h1 W)
        NODE2(3,  2, r1, h0, r2);             // h3 = softplus((h2+h0) W)
        NODE3(4,  3, r2, r0, h0, r3);         // h4 = sin((h3+h1+h0) W)
        NODE2(5,  4, r3, r1, r0);             // h5 = gauss((h4+h2) W)
        NODE2(6,  5, r0, r2, r1);             // h6 = sigmoid((h5+h3) W)
        NODE2(7,  0, r1, r3, r2);             // h7 = tanh((h6+h4) W)
        NODE3(8,  1, r2, r0, h0, r3);         // h8 = elu((h7+h5+h0) W)
        NODE2(9,  2, r3, r1, r0);             // h9 = softplus((h8+h6) W)
        NODE2(10, 3, r0, r2, r1);             // h10= sin((h9+h7) W)
        NODE2(11, 4, r1, r3, r2);             // h11= gauss((h10+h8) W)

        // ---- output: sigmoid(h11 @ W_out + b_out), h11 in r2 ----
        {
            f32x4 om = (f32x4){0.f, 0.f, 0.f, 0.f};
            om = MFMA(*(const f16x8*)&ofrag[0][lane][0], r2[0], om);
            om = MFMA(*(const f16x8*)&ofrag[1][lane][0], r2[1], om);
            if (q == 0){
                #pragma unroll
                for (int r_ = 0; r_ < 3; ++r_)
                    out[(size_t)myp * 3 + r_] = act_sigmoid(om[r_] + bout_s[r_]);
            }
        }
    }
    #undef NODE_CORE
    #undef NODE1
    #undef NODE2
    #undef NODE3
}

extern "C" void kernel_launch(void* const* d_in, const int* in_sizes, int n_in,
                              void* d_out, int out_size, void* d_ws, size_t ws_size,
                              hipStream_t stream)
{
    const float* x       = (const float*)d_in[0];
    const float* y       = (const float*)d_in[1];
    const float* z       = (const float*)d_in[2];
    const float* r       = (const float*)d_in[3];
    const float* noise   = (const float*)d_in[4];
    const float* W_noise = (const float*)d_in[5];
    const float* b_noise = (const float*)d_in[6];
    const float* W_x     = (const float*)d_in[7];
    const float* W_y     = (const float*)d_in[8];
    const float* W_z     = (const float*)d_in[9];
    const float* W_r     = (const float*)d_in[10];
    const float* W1      = (const float*)d_in[11];
    const float* b1      = (const float*)d_in[12];
    const float* Wg      = (const float*)d_in[13];
    const float* bg      = (const float*)d_in[14];
    const float* W_out   = (const float*)d_in[15];
    const float* b_out   = (const float*)d_in[16];
    float* out = (float*)d_out;

    const int n = in_sizes[0];
    const int blocks = n / 512;         // 512 points per block (8 waves x 16 pts x 4 iters)
    inr_mfma2_kernel<<<dim3(blocks), dim3(512), 0, stream>>>(
        x, y, z, r, noise, W_noise, b_noise, W_x, W_y, W_z, W_r,
        W1, b1, Wg, bg, W_out, b_out, out);
}

// Round 5
// 194.658 us; speedup vs baseline: 4.5865x; 1.0595x over previous
//
#include <hip/hip_runtime.h>

#define SCR 72     // scratch feature stride (f16): 144 B rows, 16B-aligned
#define WRS 65     // staged fp32 weight row stride (floats): breaks 16-way bank conflicts in frag-fill

typedef _Float16 f16;
typedef f16  f16x2 __attribute__((ext_vector_type(2)));
typedef f16  f16x4 __attribute__((ext_vector_type(4)));
typedef f16  f16x8 __attribute__((ext_vector_type(8)));
typedef __fp16 h16x2 __attribute__((ext_vector_type(2)));  // cvt_pkrtz native return type
typedef float f32x4 __attribute__((ext_vector_type(4)));

__device__ __forceinline__ float frcp(float x){
#if __has_builtin(__builtin_amdgcn_rcpf)
    return __builtin_amdgcn_rcpf(x);
#else
    return 1.0f / x;
#endif
}

// ---------- activations (fp32, rcp-based — no v_div sequences) ----------
__device__ __forceinline__ float act_tanh(float x){
    return 1.0f - 2.0f * frcp(1.0f + __expf(2.0f * x));
}
__device__ __forceinline__ float act_elu(float x){
    float e = __expf(x) - 1.0f;
    return x > 0.0f ? x : e;
}
__device__ __forceinline__ float act_softplus(float x){
    float a = fabsf(x);
    return fmaxf(x, 0.0f) + __logf(1.0f + __expf(-a));
}
__device__ __forceinline__ float act_gauss(float x){
    return __expf(-0.5f * x * x);
}
__device__ __forceinline__ float act_sigmoid(float x){
    return frcp(1.0f + __expf(-x));
}
template<int A> __device__ __forceinline__ float act(float v){
    if constexpr (A == 0) return act_tanh(v);
    else if constexpr (A == 1) return act_elu(v);
    else if constexpr (A == 2) return act_softplus(v);
    else if constexpr (A == 3) return __sinf(v);
    else if constexpr (A == 4) return act_gauss(v);
    else                       return act_sigmoid(v);
}

__device__ __forceinline__ f16x2 cvt2(float a, float b){
    h16x2 p = __builtin_amdgcn_cvt_pkrtz(a, b);
    return __builtin_bit_cast(f16x2, p);
}
__device__ __forceinline__ f16x4 pack4(float a, float b, float c, float d){
    f16x2 p0 = cvt2(a, b);
    f16x2 p1 = cvt2(c, d);
    f16x4 r; r[0] = p0[0]; r[1] = p0[1]; r[2] = p1[0]; r[3] = p1[1];
    return r;
}

#define MFMA(a, b, c) __builtin_amdgcn_mfma_f32_16x16x32_f16((a), (b), (c), 0, 0, 0)

__global__ __launch_bounds__(1024, 1) void inr_mfma3_kernel(
    const float* __restrict__ gx, const float* __restrict__ gy,
    const float* __restrict__ gz, const float* __restrict__ gr,
    const float* __restrict__ gnoise,
    const float* __restrict__ W_noise, const float* __restrict__ b_noise,
    const float* __restrict__ W_x, const float* __restrict__ W_y,
    const float* __restrict__ W_z, const float* __restrict__ W_r,
    const float* __restrict__ W1, const float* __restrict__ b1,
    const float* __restrict__ Wg, const float* __restrict__ bg,
    const float* __restrict__ W_out, const float* __restrict__ b_out,
    float* __restrict__ out)
{
    // ---- LDS: ~142 KB total, 1 block (16 waves) per CU -> 4 waves/SIMD ----
    __shared__ __align__(16) f16   wfrag[12][4][2][64][8]; // 96 KB  W^T A-frags [node][t][s][lane][j]
    __shared__ __align__(16) f16   nfrag[4][64][8];        //  4 KB  W_noise^T (+bias row k=16)
    __shared__ __align__(16) f16   ofrag[2][64][8];        //  2 KB  W_out^T (rows >=3 zero)
    __shared__ __align__(16) float bfrag[12][4][4][4];     //  3 KB  biases in frag order
    __shared__ __align__(16) float wvfrag[4][4][4][4];     //  1 KB  Wx,Wy,Wz,Wr in frag order
    __shared__            float bout_s[4];
    __shared__ __align__(16) f16   scratch[16][16][SCR];   // 36.9 KB per-wave transpose scratch

    const int tid  = threadIdx.x;
    const int lane = tid & 63;
    const int wvid = tid >> 6;       // wave id 0..15
    const int n    = lane & 15;      // point-in-tile (MFMA col)
    const int q    = lane >> 4;      // quad

    // ================= PREP: build fragments in LDS =================
    if (tid < 12 * 64){
        int node = tid >> 6, f = tid & 63;
        bfrag[node][(f >> 4) & 3][(f >> 2) & 3][f & 3] = (node == 0) ? b1[f] : bg[(node - 1) * 64 + f];
    }
    if (tid < 4 * 64){
        int vec = tid >> 6, f = tid & 63;
        const float* src = (vec == 0) ? W_x : (vec == 1) ? W_y : (vec == 2) ? W_z : W_r;
        wvfrag[vec][(f >> 4) & 3][(f >> 2) & 3][f & 3] = src[f];
    }
    if (tid < 4) bout_s[tid] = (tid < 3) ? b_out[tid] : 0.0f;
    for (int i = tid; i < 2048; i += 1024){          // nfrag
        int j = i & 7, ln = (i >> 3) & 63, t = i >> 9;
        int k = ((ln >> 4) & 3) * 8 + j, m = t * 16 + (ln & 15);
        float v = (k < 16) ? W_noise[k * 64 + m] : ((k == 16) ? b_noise[m] : 0.0f);
        nfrag[t][ln][j] = (f16)v;
    }
    if (tid < 1024){                                  // ofrag
        int j = tid & 7, ln = (tid >> 3) & 63, s = tid >> 9;
        int k = s * 32 + ((ln >> 4) & 3) * 8 + j, c = ln & 15;
        float v = (c < 3) ? W_out[k * 3 + c] : 0.0f;
        ofrag[s][ln][j] = (f16)v;
    }
    // big weights: coalesced stage into padded scratch (raw fp32), then frag-fill
    {
        float* wraw = (float*)&scratch[0][0][0];     // 64*65*4 = 16.6 KB <= 36.9 KB
        for (int node = 0; node < 12; ++node){
            const float* Wsrc = (node == 0) ? W1 : (Wg + (node - 1) * 4096);
            __syncthreads();                          // protect wraw (prev iter readers)
            {
                float4 v = ((const float4*)Wsrc)[tid];    // 1024 float4 = full 64x64
                const int row = tid >> 4, col = (tid & 15) * 4;
                float* dst = wraw + row * WRS + col;      // padded row: no vec store (odd stride)
                dst[0] = v.x; dst[1] = v.y; dst[2] = v.z; dst[3] = v.w;
            }
            __syncthreads();
            const int L  = tid * 4;                   // 4096 f16 per node, 4 per thread
            const int j0 = L & 7;                     // 0 or 4 -> 8B-aligned f16x4 store
            const int ln = (L >> 3) & 63;
            const int s  = (L >> 9) & 1;
            const int t  = L >> 10;
            const int kb = ((ln >> 4) & 3) * 8 + s * 32 + j0;
            const int m  = t * 16 + (ln & 15);
            f16x4 vvv;
            #pragma unroll
            for (int j = 0; j < 4; ++j) vvv[j] = (f16)wraw[(kb + j) * WRS + m];
            *(f16x4*)&wfrag[node][t][s][ln][j0] = vvv;
        }
        __syncthreads();   // wfrag complete; scratch now free for per-wave use
    }

    // lane-constant scratch pointers (all steady-state offsets are immediates)
    f16*       swb = &scratch[wvid][n][4 * q];   // write: feat 16t+4q  -> swb + 16t
    const f16* srb = &scratch[wvid][n][8 * q];   // read:  feat 32s+8q  -> srb + 32s

    // one node: acc = bias; acc += W^T @ Bin (8 MFMAs); act; transpose via scratch -> OUT frags
    #define NODE_CORE(NI, ACTI, B0, B1, OUT) do {                                          \
        f32x4 ac_[4];                                                                      \
        _Pragma("unroll")                                                                  \
        for (int t_ = 0; t_ < 4; ++t_) ac_[t_] = *(const f32x4*)&bfrag[NI][t_][q][0];      \
        _Pragma("unroll")                                                                  \
        for (int t_ = 0; t_ < 4; ++t_)                                                     \
            ac_[t_] = MFMA(*(const f16x8*)&wfrag[NI][t_][0][lane][0], B0, ac_[t_]);        \
        _Pragma("unroll")                                                                  \
        for (int t_ = 0; t_ < 4; ++t_)                                                     \
            ac_[t_] = MFMA(*(const f16x8*)&wfrag[NI][t_][1][lane][0], B1, ac_[t_]);        \
        _Pragma("unroll")                                                                  \
        for (int t_ = 0; t_ < 4; ++t_)                                                     \
            *(f16x4*)(swb + 16 * t_) = pack4(act<ACTI>(ac_[t_][0]), act<ACTI>(ac_[t_][1]), \
                                             act<ACTI>(ac_[t_][2]), act<ACTI>(ac_[t_][3]));\
        OUT[0] = *(const f16x8*)(srb);                                                     \
        OUT[1] = *(const f16x8*)(srb + 32);                                                \
    } while (0)

    #define NODE1(NI, ACTI, A, OUT)       do { NODE_CORE(NI, ACTI, A[0], A[1], OUT); } while (0)
    #define NODE2(NI, ACTI, A, B, OUT)    do { f16x8 s0_ = A[0] + B[0], s1_ = A[1] + B[1];          \
                                               NODE_CORE(NI, ACTI, s0_, s1_, OUT); } while (0)
    #define NODE3(NI, ACTI, A, B, C, OUT) do { f16x8 s0_ = A[0] + B[0] + C[0],                      \
                                                     s1_ = A[1] + B[1] + C[1];                      \
                                               NODE_CORE(NI, ACTI, s0_, s1_, OUT); } while (0)

    // ================= MAIN LOOP: 2 tiles of 16 points per wave =================
    for (int iter = 0; iter < 2; ++iter){
        const int tile = blockIdx.x * 32 + iter * 16 + wvid;
        const int myp  = tile * 16 + n;

        // ---- input branches ----
        const float xs = gx[myp], ys = gy[myp], zs = gz[myp], rs = gr[myp];
        f16x8 nb;
        if (q < 2){
            const float4 a4 = *(const float4*)(gnoise + (size_t)myp * 16 + q * 8);
            const float4 b4 = *(const float4*)(gnoise + (size_t)myp * 16 + q * 8 + 4);
            f16x2 p0 = cvt2(a4.x, a4.y);
            f16x2 p1 = cvt2(a4.z, a4.w);
            f16x2 p2 = cvt2(b4.x, b4.y);
            f16x2 p3 = cvt2(b4.z, b4.w);
            nb[0] = p0[0]; nb[1] = p0[1]; nb[2] = p1[0]; nb[3] = p1[1];
            nb[4] = p2[0]; nb[5] = p2[1]; nb[6] = p3[0]; nb[7] = p3[1];
        } else {
            #pragma unroll
            for (int j = 0; j < 8; ++j) nb[j] = (f16)0.0f;
            if (q == 2) nb[0] = (f16)1.0f;   // bias row k=16
        }
        // g = sin(elu(z Wz) + gauss(x Wx) + tanh(y Wy) + softplus(r Wr) + tanh(noise Wn + bn))
        float gv[4][4];
        {
            f32x4 am[4];
            #pragma unroll
            for (int t_ = 0; t_ < 4; ++t_){
                f32x4 zz = (f32x4){0.f, 0.f, 0.f, 0.f};
                am[t_] = MFMA(*(const f16x8*)&nfrag[t_][lane][0], nb, zz);
            }
            #pragma unroll
            for (int t_ = 0; t_ < 4; ++t_){
                const float4 wx = *(const float4*)&wvfrag[0][t_][q][0];
                const float4 wy = *(const float4*)&wvfrag[1][t_][q][0];
                const float4 wz = *(const float4*)&wvfrag[2][t_][q][0];
                const float4 wr = *(const float4*)&wvfrag[3][t_][q][0];
                const float wxa[4] = {wx.x, wx.y, wx.z, wx.w};
                const float wya[4] = {wy.x, wy.y, wy.z, wy.w};
                const float wza[4] = {wz.x, wz.y, wz.z, wz.w};
                const float wra[4] = {wr.x, wr.y, wr.z, wr.w};
                #pragma unroll
                for (int r_ = 0; r_ < 4; ++r_){
                    float v = act_elu(zs * wza[r_])
                            + act_gauss(xs * wxa[r_])
                            + act_tanh(ys * wya[r_])
                            + act_softplus(rs * wra[r_])
                            + act_tanh(am[t_][r_]);
                    gv[t_][r_] = __sinf(v);
                }
            }
        }
        f16x8 sg[2];
        #pragma unroll
        for (int t_ = 0; t_ < 4; ++t_)
            *(f16x4*)(swb + 16 * t_) = pack4(gv[t_][0], gv[t_][1], gv[t_][2], gv[t_][3]);
        sg[0] = *(const f16x8*)(srb);
        sg[1] = *(const f16x8*)(srb + 32);

        f16x8 h0[2], r0[2], r1[2], r2[2], r3[2];
        NODE1(0,  0, sg, h0);                 // h0 = tanh(g @ W1 + b1)
        NODE1(1,  0, h0, r0);                 // h1 = tanh(h0 W)
        NODE1(2,  1, r0, r1);                 // h2 = elu(h1 W)
        NODE2(3,  2, r1, h0, r2);             // h3 = softplus((h2+h0) W)
        NODE3(4,  3, r2, r0, h0, r3);         // h4 = sin((h3+h1+h0) W)
        NODE2(5,  4, r3, r1, r0);             // h5 = gauss((h4+h2) W)
        NODE2(6,  5, r0, r2, r1);             // h6 = sigmoid((h5+h3) W)
        NODE2(7,  0, r1, r3, r2);             // h7 = tanh((h6+h4) W)
        NODE3(8,  1, r2, r0, h0, r3);         // h8 = elu((h7+h5+h0) W)
        NODE2(9,  2, r3, r1, r0);             // h9 = softplus((h8+h6) W)
        NODE2(10, 3, r0, r2, r1);             // h10= sin((h9+h7) W)
        NODE2(11, 4, r1, r3, r2);             // h11= gauss((h10+h8) W)

        // ---- output: sigmoid(h11 @ W_out + b_out), h11 in r2 ----
        {
            f32x4 om = (f32x4){0.f, 0.f, 0.f, 0.f};
            om = MFMA(*(const f16x8*)&ofrag[0][lane][0], r2[0], om);
            om = MFMA(*(const f16x8*)&ofrag[1][lane][0], r2[1], om);
            if (q == 0){
                #pragma unroll
                for (int r_ = 0; r_ < 3; ++r_)
                    out[(size_t)myp * 3 + r_] = act_sigmoid(om[r_] + bout_s[r_]);
            }
        }
    }
    #undef NODE_CORE
    #undef NODE1
    #undef NODE2
    #undef NODE3
}

extern "C" void kernel_launch(void* const* d_in, const int* in_sizes, int n_in,
                              void* d_out, int out_size, void* d_ws, size_t ws_size,
                              hipStream_t stream)
{
    const float* x       = (const float*)d_in[0];
    const float* y       = (const float*)d_in[1];
    const float* z       = (const float*)d_in[2];
    const float* r       = (const float*)d_in[3];
    const float* noise   = (const float*)d_in[4];
    const float* W_noise = (const float*)d_in[5];
    const float* b_noise = (const float*)d_in[6];
    const float* W_x     = (const float*)d_in[7];
    const float* W_y     = (const float*)d_in[8];
    const float* W_z     = (const float*)d_in[9];
    const float* W_r     = (const float*)d_in[10];
    const float* W1      = (const float*)d_in[11];
    const float* b1      = (const float*)d_in[12];
    const float* Wg      = (const float*)d_in[13];
    const float* bg      = (const float*)d_in[14];
    const float* W_out   = (const float*)d_in[15];
    const float* b_out   = (const float*)d_in[16];
    float* out = (float*)d_out;

    const int n = in_sizes[0];
    const int blocks = n / 512;   // 512 points per block (16 waves x 16 pts x 2 iters)
    inr_mfma3_kernel<<<dim3(blocks), dim3(1024), 0, stream>>>(
        x, y, z, r, noise, W_noise, b_noise, W_x, W_y, W_z, W_r,
        W1, b1, Wg, bg, W_out, b_out, out);
}

// Round 6
// 194.018 us; speedup vs baseline: 4.6016x; 1.0033x over previous
//
#include <hip/hip_runtime.h>

#define SCR 72     // scratch feature stride (f16): 144 B rows, 16B-aligned
#define WRS 65     // staged fp32 weight row stride (floats): breaks 16-way bank conflicts in frag-fill

typedef _Float16 f16;
typedef f16  f16x2 __attribute__((ext_vector_type(2)));
typedef f16  f16x4 __attribute__((ext_vector_type(4)));
typedef f16  f16x8 __attribute__((ext_vector_type(8)));
typedef __fp16 h16x2 __attribute__((ext_vector_type(2)));  // cvt_pkrtz native return type
typedef float f32x4 __attribute__((ext_vector_type(4)));

__device__ __forceinline__ float frcp(float x){
#if __has_builtin(__builtin_amdgcn_rcpf)
    return __builtin_amdgcn_rcpf(x);
#else
    return 1.0f / x;
#endif
}

// ---------- activations (fp32, rcp-based — no v_div sequences) ----------
__device__ __forceinline__ float act_tanh(float x){
    return 1.0f - 2.0f * frcp(1.0f + __expf(2.0f * x));
}
__device__ __forceinline__ float act_elu(float x){
    float e = __expf(x) - 1.0f;
    return x > 0.0f ? x : e;
}
__device__ __forceinline__ float act_softplus(float x){
    float a = fabsf(x);
    return fmaxf(x, 0.0f) + __logf(1.0f + __expf(-a));
}
__device__ __forceinline__ float act_gauss(float x){
    return __expf(-0.5f * x * x);
}
__device__ __forceinline__ float act_sigmoid(float x){
    return frcp(1.0f + __expf(-x));
}
template<int A> __device__ __forceinline__ float act(float v){
    if constexpr (A == 0) return act_tanh(v);
    else if constexpr (A == 1) return act_elu(v);
    else if constexpr (A == 2) return act_softplus(v);
    else if constexpr (A == 3) return __sinf(v);
    else if constexpr (A == 4) return act_gauss(v);
    else                       return act_sigmoid(v);
}

__device__ __forceinline__ f16x2 cvt2(float a, float b){
    h16x2 p = __builtin_amdgcn_cvt_pkrtz(a, b);
    return __builtin_bit_cast(f16x2, p);
}
__device__ __forceinline__ f16x4 pack4(float a, float b, float c, float d){
    f16x2 p0 = cvt2(a, b);
    f16x2 p1 = cvt2(c, d);
    f16x4 r; r[0] = p0[0]; r[1] = p0[1]; r[2] = p1[0]; r[3] = p1[1];
    return r;
}

#define MFMA(a, b, c) __builtin_amdgcn_mfma_f32_16x16x32_f16((a), (b), (c), 0, 0, 0)

// one node for one 16-pt tile: acc=bias; acc += W^T @ B (8 MFMAs); act; LDS transpose -> OUT frags
template<int ACTI>
__device__ __forceinline__ void node_core(const f16* __restrict__ wr, const float* __restrict__ bf,
                                          const f16x8 B0, const f16x8 B1,
                                          f16* swb, const f16* srb, f16x8 OUT[2])
{
    f32x4 ac[4];
    #pragma unroll
    for (int t = 0; t < 4; ++t) ac[t] = *(const f32x4*)(bf + 16 * t);
    #pragma unroll
    for (int t = 0; t < 4; ++t) ac[t] = MFMA(*(const f16x8*)(wr + t * 1024), B0, ac[t]);
    #pragma unroll
    for (int t = 0; t < 4; ++t) ac[t] = MFMA(*(const f16x8*)(wr + t * 1024 + 512), B1, ac[t]);
    #pragma unroll
    for (int t = 0; t < 4; ++t)
        *(f16x4*)(swb + 16 * t) = pack4(act<ACTI>(ac[t][0]), act<ACTI>(ac[t][1]),
                                        act<ACTI>(ac[t][2]), act<ACTI>(ac[t][3]));
    OUT[0] = *(const f16x8*)(srb);
    OUT[1] = *(const f16x8*)(srb + 32);
}

__global__ __launch_bounds__(1024, 1) void inr_mfma4_kernel(
    const float* __restrict__ gx, const float* __restrict__ gy,
    const float* __restrict__ gz, const float* __restrict__ gr,
    const float* __restrict__ gnoise,
    const float* __restrict__ W_noise, const float* __restrict__ b_noise,
    const float* __restrict__ W_x, const float* __restrict__ W_y,
    const float* __restrict__ W_z, const float* __restrict__ W_r,
    const float* __restrict__ W1, const float* __restrict__ b1,
    const float* __restrict__ Wg, const float* __restrict__ bg,
    const float* __restrict__ W_out, const float* __restrict__ b_out,
    float* __restrict__ out)
{
    // ---- LDS: ~142 KB total, 1 block (16 waves) per CU -> 4 waves/SIMD ----
    __shared__ __align__(16) f16   wfrag[12][4][2][64][8]; // 96 KB  W^T A-frags [node][t][s][lane][j]
    __shared__ __align__(16) f16   nfrag[4][64][8];        //  4 KB  W_noise^T (+bias row k=16)
    __shared__ __align__(16) f16   ofrag[2][64][8];        //  2 KB  W_out^T (rows >=3 zero)
    __shared__ __align__(16) float bfrag[12][4][4][4];     //  3 KB  biases in frag order
    __shared__ __align__(16) float wvfrag[4][4][4][4];     //  1 KB  Wx,Wy,Wz,Wr in frag order
    __shared__            float bout_s[4];
    __shared__ __align__(16) f16   scratch[16][16][SCR];   // 36.9 KB per-wave transpose scratch

    const int tid  = threadIdx.x;
    const int lane = tid & 63;
    const int wvid = tid >> 6;       // wave id 0..15
    const int n    = lane & 15;      // point-in-tile (MFMA col)
    const int q    = lane >> 4;      // quad

    // ================= PREP: build fragments in LDS (once per CU: grid=256) =================
    if (tid < 12 * 64){
        int node = tid >> 6, f = tid & 63;
        bfrag[node][(f >> 4) & 3][(f >> 2) & 3][f & 3] = (node == 0) ? b1[f] : bg[(node - 1) * 64 + f];
    }
    if (tid < 4 * 64){
        int vec = tid >> 6, f = tid & 63;
        const float* src = (vec == 0) ? W_x : (vec == 1) ? W_y : (vec == 2) ? W_z : W_r;
        wvfrag[vec][(f >> 4) & 3][(f >> 2) & 3][f & 3] = src[f];
    }
    if (tid < 4) bout_s[tid] = (tid < 3) ? b_out[tid] : 0.0f;
    for (int i = tid; i < 2048; i += 1024){          // nfrag
        int j = i & 7, ln = (i >> 3) & 63, t = i >> 9;
        int k = ((ln >> 4) & 3) * 8 + j, m = t * 16 + (ln & 15);
        float v = (k < 16) ? W_noise[k * 64 + m] : ((k == 16) ? b_noise[m] : 0.0f);
        nfrag[t][ln][j] = (f16)v;
    }
    {                                                 // ofrag
        int j = tid & 7, ln = (tid >> 3) & 63, s = tid >> 9;
        int k = s * 32 + ((ln >> 4) & 3) * 8 + j, c = ln & 15;
        float v = (c < 3) ? W_out[k * 3 + c] : 0.0f;
        ofrag[s][ln][j] = (f16)v;
    }
    // big weights: coalesced stage into padded scratch (raw fp32), then frag-fill
    {
        float* wraw = (float*)&scratch[0][0][0];     // 64*65*4 = 16.6 KB <= 36.9 KB
        for (int node = 0; node < 12; ++node){
            const float* Wsrc = (node == 0) ? W1 : (Wg + (node - 1) * 4096);
            __syncthreads();                          // protect wraw (prev iter readers)
            {
                float4 v = ((const float4*)Wsrc)[tid];    // 1024 float4 = full 64x64
                const int row = tid >> 4, col = (tid & 15) * 4;
                float* dst = wraw + row * WRS + col;
                dst[0] = v.x; dst[1] = v.y; dst[2] = v.z; dst[3] = v.w;
            }
            __syncthreads();
            const int L  = tid * 4;                   // 4096 f16 per node, 4 per thread
            const int j0 = L & 7;
            const int ln = (L >> 3) & 63;
            const int s  = (L >> 9) & 1;
            const int t  = L >> 10;
            const int kb = ((ln >> 4) & 3) * 8 + s * 32 + j0;
            const int m  = t * 16 + (ln & 15);
            f16x4 vvv;
            #pragma unroll
            for (int j = 0; j < 4; ++j) vvv[j] = (f16)wraw[(kb + j) * WRS + m];
            *(f16x4*)&wfrag[node][t][s][ln][j0] = vvv;
        }
        __syncthreads();   // wfrag complete; scratch now free for per-wave use
    }

    // lane-constant scratch pointers (steady-state offsets are immediates)
    f16*       swb = &scratch[wvid][n][4 * q];   // write: feat 16t+4q  -> swb + 16t
    const f16* srb = &scratch[wvid][n][8 * q];   // read:  feat 32s+8q  -> srb + 32s

    #define WPTR(NI) (&wfrag[NI][0][0][lane][0])
    #define BPTR(NI) (&bfrag[NI][0][q][0])

    // dual-tile node wrappers: A,B,C are f16x8[2][2] rings ([tile][s])
    #define N1(NI, ACTI, A, OUT) do {                                                  \
        _Pragma("unroll")                                                              \
        for (int tt = 0; tt < 2; ++tt)                                                 \
            node_core<ACTI>(WPTR(NI), BPTR(NI), A[tt][0], A[tt][1], swb, srb, OUT[tt]);\
    } while (0)
    #define N2(NI, ACTI, A, B, OUT) do {                                               \
        _Pragma("unroll")                                                              \
        for (int tt = 0; tt < 2; ++tt){                                                \
            f16x8 s0_ = A[tt][0] + B[tt][0], s1_ = A[tt][1] + B[tt][1];                \
            node_core<ACTI>(WPTR(NI), BPTR(NI), s0_, s1_, swb, srb, OUT[tt]);          \
        }                                                                              \
    } while (0)
    #define N3(NI, ACTI, A, B, C, OUT) do {                                            \
        _Pragma("unroll")                                                              \
        for (int tt = 0; tt < 2; ++tt){                                                \
            f16x8 s0_ = A[tt][0] + B[tt][0] + C[tt][0];                                \
            f16x8 s1_ = A[tt][1] + B[tt][1] + C[tt][1];                                \
            node_core<ACTI>(WPTR(NI), BPTR(NI), s0_, s1_, swb, srb, OUT[tt]);          \
        }                                                                              \
    } while (0)

    // ================= MAIN LOOP: 2 iters x 2 tiles of 16 points per wave =================
    for (int iter = 0; iter < 2; ++iter){
        f16x8 sg[2][2], h0[2][2], r0[2][2], r1[2][2], r2[2][2], r3[2][2];
        int myp_[2];

        #pragma unroll
        for (int tt = 0; tt < 2; ++tt){
            const int tile = blockIdx.x * 64 + iter * 32 + wvid * 2 + tt;
            const int myp  = tile * 16 + n;
            myp_[tt] = myp;

            // ---- input branches ----
            const float xs = gx[myp], ys = gy[myp], zs = gz[myp], rs = gr[myp];
            f16x8 nb;
            if (q < 2){
                const float4 a4 = *(const float4*)(gnoise + (size_t)myp * 16 + q * 8);
                const float4 b4 = *(const float4*)(gnoise + (size_t)myp * 16 + q * 8 + 4);
                f16x2 p0 = cvt2(a4.x, a4.y);
                f16x2 p1 = cvt2(a4.z, a4.w);
                f16x2 p2 = cvt2(b4.x, b4.y);
                f16x2 p3 = cvt2(b4.z, b4.w);
                nb[0] = p0[0]; nb[1] = p0[1]; nb[2] = p1[0]; nb[3] = p1[1];
                nb[4] = p2[0]; nb[5] = p2[1]; nb[6] = p3[0]; nb[7] = p3[1];
            } else {
                #pragma unroll
                for (int j = 0; j < 8; ++j) nb[j] = (f16)0.0f;
                if (q == 2) nb[0] = (f16)1.0f;   // bias row k=16
            }
            // g = sin(elu(z Wz) + gauss(x Wx) + tanh(y Wy) + softplus(r Wr) + tanh(noise Wn + bn))
            float gv[4][4];
            {
                f32x4 am[4];
                #pragma unroll
                for (int t_ = 0; t_ < 4; ++t_){
                    f32x4 zz = (f32x4){0.f, 0.f, 0.f, 0.f};
                    am[t_] = MFMA(*(const f16x8*)&nfrag[t_][lane][0], nb, zz);
                }
                #pragma unroll
                for (int t_ = 0; t_ < 4; ++t_){
                    const float4 wx = *(const float4*)&wvfrag[0][t_][q][0];
                    const float4 wy = *(const float4*)&wvfrag[1][t_][q][0];
                    const float4 wz = *(const float4*)&wvfrag[2][t_][q][0];
                    const float4 wr = *(const float4*)&wvfrag[3][t_][q][0];
                    const float wxa[4] = {wx.x, wx.y, wx.z, wx.w};
                    const float wya[4] = {wy.x, wy.y, wy.z, wy.w};
                    const float wza[4] = {wz.x, wz.y, wz.z, wz.w};
                    const float wra[4] = {wr.x, wr.y, wr.z, wr.w};
                    #pragma unroll
                    for (int r_ = 0; r_ < 4; ++r_){
                        float v = act_elu(zs * wza[r_])
                                + act_gauss(xs * wxa[r_])
                                + act_tanh(ys * wya[r_])
                                + act_softplus(rs * wra[r_])
                                + act_tanh(am[t_][r_]);
                        gv[t_][r_] = __sinf(v);
                    }
                }
            }
            #pragma unroll
            for (int t_ = 0; t_ < 4; ++t_)
                *(f16x4*)(swb + 16 * t_) = pack4(gv[t_][0], gv[t_][1], gv[t_][2], gv[t_][3]);
            sg[tt][0] = *(const f16x8*)(srb);
            sg[tt][1] = *(const f16x8*)(srb + 32);
        }

        N1(0,  0, sg, h0);                 // h0 = tanh(g @ W1 + b1)
        N1(1,  0, h0, r0);                 // h1 = tanh(h0 W)
        N1(2,  1, r0, r1);                 // h2 = elu(h1 W)
        N2(3,  2, r1, h0, r2);             // h3 = softplus((h2+h0) W)
        N3(4,  3, r2, r0, h0, r3);         // h4 = sin((h3+h1+h0) W)
        N2(5,  4, r3, r1, r0);             // h5 = gauss((h4+h2) W)
        N2(6,  5, r0, r2, r1);             // h6 = sigmoid((h5+h3) W)
        N2(7,  0, r1, r3, r2);             // h7 = tanh((h6+h4) W)
        N3(8,  1, r2, r0, h0, r3);         // h8 = elu((h7+h5+h0) W)
        N2(9,  2, r3, r1, r0);             // h9 = softplus((h8+h6) W)
        N2(10, 3, r0, r2, r1);             // h10= sin((h9+h7) W)
        N2(11, 4, r1, r3, r2);             // h11= gauss((h10+h8) W)

        // ---- output: sigmoid(h11 @ W_out + b_out), h11 in r2 ----
        #pragma unroll
        for (int tt = 0; tt < 2; ++tt){
            f32x4 om = (f32x4){0.f, 0.f, 0.f, 0.f};
            om = MFMA(*(const f16x8*)&ofrag[0][lane][0], r2[tt][0], om);
            om = MFMA(*(const f16x8*)&ofrag[1][lane][0], r2[tt][1], om);
            if (q == 0){
                #pragma unroll
                for (int r_ = 0; r_ < 3; ++r_)
                    out[(size_t)myp_[tt] * 3 + r_] = act_sigmoid(om[r_] + bout_s[r_]);
            }
        }
    }
    #undef N1
    #undef N2
    #undef N3
    #undef WPTR
    #undef BPTR
}

extern "C" void kernel_launch(void* const* d_in, const int* in_sizes, int n_in,
                              void* d_out, int out_size, void* d_ws, size_t ws_size,
                              hipStream_t stream)
{
    const float* x       = (const float*)d_in[0];
    const float* y       = (const float*)d_in[1];
    const float* z       = (const float*)d_in[2];
    const float* r       = (const float*)d_in[3];
    const float* noise   = (const float*)d_in[4];
    const float* W_noise = (const float*)d_in[5];
    const float* b_noise = (const float*)d_in[6];
    const float* W_x     = (const float*)d_in[7];
    const float* W_y     = (const float*)d_in[8];
    const float* W_z     = (const float*)d_in[9];
    const float* W_r     = (const float*)d_in[10];
    const float* W1      = (const float*)d_in[11];
    const float* b1      = (const float*)d_in[12];
    const float* Wg      = (const float*)d_in[13];
    const float* bg      = (const float*)d_in[14];
    const float* W_out   = (const float*)d_in[15];
    const float* b_out   = (const float*)d_in[16];
    float* out = (float*)d_out;

    const int n = in_sizes[0];
    const int blocks = n / 1024;  // 1024 pts/block (16 waves x 2 tiles x 16 pts x 2 iters); grid=256 -> prep once/CU
    inr_mfma4_kernel<<<dim3(blocks), dim3(1024), 0, stream>>>(
        x, y, z, r, noise, W_noise, b_noise, W_x, W_y, W_z, W_r,
        W1, b1, Wg, bg, W_out, b_out, out);
}